// Round 1
// baseline (1381.005 us; speedup 1.0000x reference)
//
#include <hip/hip_runtime.h>
#include <hip/hip_fp16.h>

#define CI 16
#define CO 48
#define DD 31
#define HH 256
#define WW 256
#define SP (HH*WW)          // 65536
#define CHUNK (DD*SP)       // 2031616 elems per channel

// ---------------- weight transpose: w[co][ci][dz][ky][kx] -> wT[(ci*3+dz)*9+t][co]
__global__ void wT_kernel(const float* __restrict__ w, float* __restrict__ wT) {
    int id = blockIdx.x * 256 + threadIdx.x;
    if (id < CO * CI * 27) {
        int co = id / (CI * 27);
        int rest = id % (CI * 27);          // ci*27 + dz*9 + t
        wT[rest * CO + co] = w[id];
    }
}

// ---------------- conv 3x3x3 (16->48) + bias + activations
// writes: Z (fp32) into zout (= d_out, reused as scratch), F1/F2 (fp16) into ws
__global__ __launch_bounds__(256)
void conv_kernel(const float* __restrict__ x,
                 const float* __restrict__ wT,
                 const float* __restrict__ b,
                 float* __restrict__ zout,
                 __half* __restrict__ f1out,
                 __half* __restrict__ f2out) {
    __shared__ float xs[3][18][18];

    const int tx = threadIdx.x;            // 0..15
    const int ty = threadIdx.y;            // 0..15
    const int tid = ty * 16 + tx;
    const int gx = blockIdx.x * 16 + tx;   // w
    const int gy = blockIdx.y * 16 + ty;   // h
    const int d  = blockIdx.z;             // depth

    const int h0 = blockIdx.y * 16 - 1;
    const int w0 = blockIdx.x * 16 - 1;

    float acc[48];
    #pragma unroll
    for (int i = 0; i < 48; ++i) acc[i] = 0.f;

    #pragma unroll 1
    for (int ci = 0; ci < CI; ++ci) {
        __syncthreads();
        for (int t = tid; t < 3 * 18 * 18; t += 256) {
            int dz = t / 324;
            int r  = (t - dz * 324) / 18;
            int cc = t - dz * 324 - r * 18;
            int gd = d + dz - 1;
            int gh = h0 + r;
            int gw = w0 + cc;
            float v = 0.f;
            if (gd >= 0 && gd < DD && (unsigned)gh < (unsigned)HH && (unsigned)gw < (unsigned)WW)
                v = x[(((size_t)ci * DD + gd) * HH + gh) * WW + gw];
            xs[dz][r][cc] = v;
        }
        __syncthreads();

        #pragma unroll
        for (int dz = 0; dz < 3; ++dz) {
            float xv[9];
            #pragma unroll
            for (int ky = 0; ky < 3; ++ky)
                #pragma unroll
                for (int kx = 0; kx < 3; ++kx)
                    xv[ky * 3 + kx] = xs[dz][ty + ky][tx + kx];

            const float* wq = wT + (size_t)(ci * 3 + dz) * 9 * CO;
            #pragma unroll
            for (int t = 0; t < 9; ++t) {
                #pragma unroll
                for (int co = 0; co < 48; ++co)
                    acc[co] = fmaf(wq[t * CO + co], xv[t], acc[co]);
            }
        }
    }

    const int sp = gy * WW + gx;
    const size_t base = (size_t)d * SP + sp;
    #pragma unroll
    for (int c = 0; c < 16; ++c) {
        float g0 = acc[c]      + b[c];
        float g1 = acc[16 + c] + b[16 + c];
        float g2 = acc[32 + c] + b[32 + c];
        // tanh via safe exp form (saturates correctly at +-inf)
        float z  = 1.f - 2.f / (__expf(2.f * g0) + 1.f);
        float f1 = 1.f / (1.f + __expf(-g1));
        float f2 = 1.f / (1.f + __expf(-g2));
        size_t o = (size_t)c * CHUNK + base;
        zout[o]  = z;
        f1out[o] = __float2half(f1);
        f2out[o] = __float2half(f2);
    }
}

// ---------------- bidirectional depth scan; one thread per (c,h,w) column
// zin aliases out (d_out) -- do NOT mark them restrict.
__global__ __launch_bounds__(256)
void scan_kernel(const float* zin,
                 const __half* __restrict__ f1in,
                 const __half* __restrict__ f2in,
                 float* out) {
    const int id = blockIdx.x * 256 + threadIdx.x;   // 0 .. 16*65536-1
    const int c = id >> 16;
    const int p = id & (SP - 1);
    const size_t base = (size_t)c * CHUNK + p;

    float z[DD], hs[DD];
    float h = 0.f;
    #pragma unroll
    for (int d = 0; d < DD; ++d) {
        float zz = zin[base + (size_t)d * SP];
        float f  = __half2float(f1in[base + (size_t)d * SP]);
        h = f * h + (1.f - f) * zz;
        z[d] = zz;
        hs[d] = h;
    }
    float hr = 0.f;
    #pragma unroll
    for (int d = DD - 1; d >= 0; --d) {
        float f = __half2float(f2in[base + (size_t)d * SP]);
        hr = f * hr + (1.f - f) * z[d];
        out[base + (size_t)d * SP] = hs[d] + hr;
    }
}

extern "C" void kernel_launch(void* const* d_in, const int* in_sizes, int n_in,
                              void* d_out, int out_size, void* d_ws, size_t ws_size,
                              hipStream_t stream) {
    const float* x = (const float*)d_in[0];
    const float* w = (const float*)d_in[1];
    const float* b = (const float*)d_in[2];
    float* out = (float*)d_out;

    char* ws = (char*)d_ws;
    const size_t half_elems = (size_t)CHUNK * 16;        // 32,505,856
    __half* f1 = (__half*)ws;
    __half* f2 = (__half*)(ws + half_elems * sizeof(__half));
    float*  wT = (float*)(ws + 2 * half_elems * sizeof(__half));
    // ws requirement: 2*65,011,712 + 82,944 bytes ~= 130.1 MB

    wT_kernel<<<(CO * CI * 27 + 255) / 256, 256, 0, stream>>>(w, wT);

    dim3 grid(WW / 16, HH / 16, DD);
    dim3 blk(16, 16, 1);
    conv_kernel<<<grid, blk, 0, stream>>>(x, wT, b, out, f1, f2);

    scan_kernel<<<(16 * SP) / 256, 256, 0, stream>>>(out, f1, f2, out);
}

// Round 3
// 590.942 us; speedup vs baseline: 2.3370x; 2.3370x over previous
//
#include <hip/hip_runtime.h>
#include <hip/hip_fp16.h>
#include <hip/hip_bf16.h>

#define CI 16
#define CO 48
#define DD 31
#define HH 256
#define WW 256
#define SP (HH*WW)          // 65536
#define CHUNK (DD*SP)       // 2031616 elems per channel
#define NTP 14              // k-steps: 28 tap-slots (27 real + 1 zero pad), 2 taps per step

typedef __bf16 bf16x8 __attribute__((ext_vector_type(8)));
typedef float  f32x4  __attribute__((ext_vector_type(4)));

// ---------------- weight prep: w[co][ci][dz][ky][kx] -> wB{h,l}[tp][co][tl*16+ci] (bf16 split)
__global__ void wprep_kernel(const float* __restrict__ w,
                             ushort* __restrict__ wBh,
                             ushort* __restrict__ wBl) {
    int id = blockIdx.x * 256 + threadIdx.x;          // NTP*CO*32 = 21504
    if (id >= NTP * CO * 32) return;
    int tp = id / (CO * 32);
    int r  = id % (CO * 32);
    int co = r / 32;
    int kk = r % 32;
    int tl = kk >> 4, ci = kk & 15;
    int tap = tp * 2 + tl;
    float v = (tap < 27) ? w[co * 432 + ci * 27 + tap] : 0.f;
    // RNE float->bf16
    uint u = __builtin_bit_cast(uint, v);
    uint hbits = (u + 0x7FFFu + ((u >> 16) & 1)) >> 16;
    float hf = __builtin_bit_cast(float, hbits << 16);
    float lres = v - hf;
    uint ul = __builtin_bit_cast(uint, lres);
    uint lbits = (ul + 0x7FFFu + ((ul >> 16) & 1)) >> 16;
    wBh[id] = (ushort)hbits;
    wBl[id] = (ushort)lbits;
}

// ---------------- conv 3x3x3 (16->48) via implicit-GEMM MFMA + bias + activations
// block: 256 thr = 4 waves; tile 16x16 pixels at depth d; wave w owns y-rows 4w..4w+3.
// LDS x-tile layout: [dz 3][yy 18][ci_half 2][xx 18][8 ci] bf16 (granule = 16B) -> A-frag
// ds_read_b128 is contiguous & conflict-free.
__global__ __launch_bounds__(256)
void conv_kernel(const float* __restrict__ x,
                 const ushort* __restrict__ wBh,
                 const ushort* __restrict__ wBl,
                 const float* __restrict__ b,
                 float* __restrict__ zout,
                 __half* __restrict__ f1out,
                 __half* __restrict__ f2out)
{
    __shared__ __align__(16) ushort xs[3 * 18 * 2 * 18 * 8];   // 31104 B

    const int tid = threadIdx.x;
    const int d   = blockIdx.z;
    const int y0  = blockIdx.y * 16;
    const int x0  = blockIdx.x * 16;

    // ---- stage x tile as bf16 ----
    for (int t = tid; t < 3 * 18 * 18 * 2; t += 256) {
        int dz = t / 648;
        int r1 = t - dz * 648;
        int yy = r1 / 36;
        int r2 = r1 - yy * 36;
        int xx = r2 >> 1;
        int hf = r2 & 1;                       // ci half
        int gd = d + dz - 1;
        int gh = y0 + yy - 1;
        int gw = x0 + xx - 1;
        uint4 q;
        uint vv[8];
        if ((unsigned)gd < DD && (unsigned)gh < HH && (unsigned)gw < WW) {
            const float* xp = x + ((size_t)(hf * 8) * DD + gd) * SP + gh * WW + gw;
            #pragma unroll
            for (int j = 0; j < 8; ++j) {
                float f = xp[(size_t)j * DD * SP];
                uint u = __builtin_bit_cast(uint, f);
                vv[j] = (u + 0x7FFFu + ((u >> 16) & 1)) >> 16;    // RNE bf16
            }
        } else {
            #pragma unroll
            for (int j = 0; j < 8; ++j) vv[j] = 0;
        }
        q.x = vv[0] | (vv[1] << 16);
        q.y = vv[2] | (vv[3] << 16);
        q.z = vv[4] | (vv[5] << 16);
        q.w = vv[6] | (vv[7] << 16);
        int g = ((dz * 18 + yy) * 2 + hf) * 18 + xx;   // layout granule index
        *(uint4*)(xs + (size_t)g * 8) = q;
    }
    __syncthreads();

    const int lane   = tid & 63;
    const int wv     = tid >> 6;
    const int xl     = lane & 15;
    const int h      = lane >> 4;       // 0..3
    const int tl     = h >> 1;          // tap-in-pair
    const int cihalf = h & 1;           // ci half for A

    f32x4 acc[4][3];
    #pragma unroll
    for (int m = 0; m < 4; ++m)
        #pragma unroll
        for (int g = 0; g < 3; ++g)
            acc[m][g] = (f32x4){0.f, 0.f, 0.f, 0.f};

    #pragma unroll 2
    for (int tp = 0; tp < NTP; ++tp) {
        int tap = tp * 2 + tl;
        if (tap > 26) tap = 26;          // pad slot: B is zero there, A value irrelevant
        int dz = tap / 9;
        int rr = tap - dz * 9;
        int ky = rr / 3;
        int kx = rr - ky * 3;

        // B fragments: contiguous 16B per lane, L1/L2-resident
        uint4 bhq[3], blq[3];
        #pragma unroll
        for (int g = 0; g < 3; ++g) {
            size_t off = (size_t)tp * 1536 + (g * 16 + xl) * 32 + 8 * h;
            bhq[g] = *(const uint4*)(wBh + off);
            blq[g] = *(const uint4*)(wBl + off);
        }

        // A base for m=0 (yy = 4*wv + ky), step per m = one yy row = 288 ushorts
        int abase = (((dz * 18 + (4 * wv + ky)) * 2 + cihalf) * 18 + (xl + kx)) * 8;

        #pragma unroll
        for (int m = 0; m < 4; ++m) {
            uint4 aq = *(const uint4*)(xs + abase + m * 288);
            bf16x8 a = __builtin_bit_cast(bf16x8, aq);
            #pragma unroll
            for (int g = 0; g < 3; ++g) {
                acc[m][g] = __builtin_amdgcn_mfma_f32_16x16x32_bf16(
                    a, __builtin_bit_cast(bf16x8, bhq[g]), acc[m][g], 0, 0, 0);
                acc[m][g] = __builtin_amdgcn_mfma_f32_16x16x32_bf16(
                    a, __builtin_bit_cast(bf16x8, blq[g]), acc[m][g], 0, 0, 0);
            }
        }
    }

    // ---- epilogue: C/D layout: c = lane&15 (channel), pixel x = 4*(lane>>4)+r
    const int c   = xl;
    const int px4 = h * 4;
    const float bz  = b[c];
    const float bf1 = b[16 + c];
    const float bf2 = b[32 + c];

    #pragma unroll
    for (int m = 0; m < 4; ++m) {
        const int gy = y0 + 4 * wv + m;
        const int gx = x0 + px4;
        const size_t base = ((size_t)c * DD + d) * SP + gy * WW + gx;
        float4 zq;
        union { __half hh[4]; uint2 u; } p1, p2;
        #pragma unroll
        for (int r = 0; r < 4; ++r) {
            float g0 = acc[m][0][r] + bz;
            float g1 = acc[m][1][r] + bf1;
            float g2 = acc[m][2][r] + bf2;
            float z  = 1.f - 2.f / (__expf(2.f * g0) + 1.f);
            float f1 = 1.f / (1.f + __expf(-g1));
            float f2 = 1.f / (1.f + __expf(-g2));
            ((float*)&zq)[r] = z;
            p1.hh[r] = __float2half(f1);
            p2.hh[r] = __float2half(f2);
        }
        *(float4*)(zout + base) = zq;
        *(uint2*)((ushort*)f1out + base) = p1.u;
        *(uint2*)((ushort*)f2out + base) = p2.u;
    }
}

// ---------------- bidirectional depth scan; one thread per (c,h,w) column
// zin aliases out (d_out) -- do NOT mark them restrict.
__global__ __launch_bounds__(256)
void scan_kernel(const float* zin,
                 const __half* __restrict__ f1in,
                 const __half* __restrict__ f2in,
                 float* out) {
    const int id = blockIdx.x * 256 + threadIdx.x;   // 0 .. 16*65536-1
    const int c = id >> 16;
    const int p = id & (SP - 1);
    const size_t base = (size_t)c * CHUNK + p;

    float z[DD], hs[DD];
    float h = 0.f;
    #pragma unroll
    for (int d = 0; d < DD; ++d) {
        float zz = zin[base + (size_t)d * SP];
        float f  = __half2float(f1in[base + (size_t)d * SP]);
        h = f * h + (1.f - f) * zz;
        z[d] = zz;
        hs[d] = h;
    }
    float hr = 0.f;
    #pragma unroll
    for (int d = DD - 1; d >= 0; --d) {
        float f = __half2float(f2in[base + (size_t)d * SP]);
        hr = f * hr + (1.f - f) * z[d];
        out[base + (size_t)d * SP] = hs[d] + hr;
    }
}

extern "C" void kernel_launch(void* const* d_in, const int* in_sizes, int n_in,
                              void* d_out, int out_size, void* d_ws, size_t ws_size,
                              hipStream_t stream) {
    const float* x = (const float*)d_in[0];
    const float* w = (const float*)d_in[1];
    const float* b = (const float*)d_in[2];
    float* out = (float*)d_out;

    char* ws = (char*)d_ws;
    const size_t half_elems = (size_t)CHUNK * 16;        // 32,505,856
    __half* f1  = (__half*)ws;
    __half* f2  = (__half*)(ws + half_elems * sizeof(__half));
    ushort* wBh = (ushort*)(ws + 2 * half_elems * sizeof(__half));
    ushort* wBl = wBh + NTP * CO * 32;
    // ws requirement: 130,023,424 + 2*43,008 B ~= 130.1 MB

    wprep_kernel<<<(NTP * CO * 32 + 255) / 256, 256, 0, stream>>>(w, wBh, wBl);

    dim3 grid(WW / 16, HH / 16, DD);
    conv_kernel<<<grid, 256, 0, stream>>>(x, wBh, wBl, b, out, f1, f2);

    scan_kernel<<<(16 * SP) / 256, 256, 0, stream>>>(out, f1, f2, out);
}